// Round 12
// baseline (1727.514 us; speedup 1.0000x reference)
//
#include <hip/hip_runtime.h>
#include <stdint.h>

typedef __attribute__((ext_vector_type(8))) short bf16x8;
typedef __attribute__((ext_vector_type(4))) float f32x4;

#define T_TOTAL 32
#define BATCH   1024
#define INDIM   784
#define HDIM    4096
#define OUTDIM  10
#define BH      (BATCH * HDIM)      // 4,194,304
#define WORDS_PER_T (BH / 64)       // 65,536 u64 words per timestep
#define TC      8                   // timesteps per GEMM chunk
#define MC      (TC * BATCH)        // 8192 rows per chunk
// concat-K layout (small-magnitude segments first, hh LAST):
// [0,784)=hm [784,1568)=mh [1568,2352)=hh [2352,2368)=0
#define KP      2368                // 37 * 64
#define DELTA   2e-3f               // near-threshold flag window (proven r9-r11)
#define FIXLIST 3072

// ---------- 2-way bf16 truncation split: a = h + m + residual(~2^-16) ----------
__device__ __forceinline__ void split2(float a, ushort& h, ushort& m) {
    unsigned ua = __float_as_uint(a);
    h = (ushort)(ua >> 16);
    float r = a - __uint_as_float(ua & 0xFFFF0000u);   // exact
    m = (ushort)(__float_as_uint(r) >> 16);
}

// ---------- split fp32 [R][784] into concat-K bf16 [R][2368] ----------
__global__ __launch_bounds__(256) void k_split3(const float* __restrict__ src,
                                                ushort* __restrict__ dst,
                                                int R, int isA) {
    int idx = blockIdx.x * 256 + threadIdx.x;
    int main_n = R * 392;                       // 784/2 pairs per row
    if (idx < main_n) {
        int row = idx / 392, kk = (idx % 392) * 2;
        float a0 = src[(size_t)row * INDIM + kk];
        float a1 = src[(size_t)row * INDIM + kk + 1];
        ushort h0, m0, h1, m1;
        split2(a0, h0, m0);
        split2(a1, h1, m1);
        ushort2 H; H.x = h0; H.y = h1;
        ushort2 M; M.x = m0; M.y = m1;
        ushort2 s1 = isA ? H : M;   // hm: A=h, B=m
        ushort2 s2 = isA ? M : H;   // mh: A=m, B=h
        ushort* d = dst + (size_t)row * KP;
        *(ushort2*)(d + kk)        = s1;  // hm
        *(ushort2*)(d + 784 + kk)  = s2;  // mh
        *(ushort2*)(d + 1568 + kk) = H;   // hh (accumulated last)
    } else if (idx < main_n + R * 8) {
        int j = idx - main_n;
        int row = j / 8, q = j % 8;
        ushort2 z; z.x = 0; z.y = 0;
        *(ushort2*)(dst + (size_t)row * KP + 2352 + q * 2) = z;
    }
}

// ---------- W2 transpose: W2[10][4096] -> W2T[4096][10] ----------
__global__ void k_transpose_w2(const float* __restrict__ W2, float* __restrict__ W2T) {
    int i = blockIdx.x * 256 + threadIdx.x;
    if (i < HDIM * OUTDIM) {
        int h = i / OUTDIM, o = i % OUTDIM;
        W2T[i] = W2[o * HDIM + h];
    }
}

// ---------- bf16 MFMA GEMM (m97 structure): Z[m][n] = A'[m][:] . B'[n][:] ----------
// 128x128 tile, BK=64, 4 waves, 4x4 frags of 16x16x32. (passed r9-r11)
__global__ __launch_bounds__(256) void k_gemm_bf16(const ushort* __restrict__ Ap,
                                                   const ushort* __restrict__ Bp,
                                                   float* __restrict__ Z) {
    __shared__ ushort Asm[128 * 64];   // [m][k] 16 KB
    __shared__ ushort Bsm[128 * 64];   // [n][k] 16 KB

    const int nwg = gridDim.x;
    const int cpx = nwg >> 3;
    const int bid = blockIdx.x;
    const int swz = (bid & 7) * cpx + (bid >> 3);
    const int bm = swz >> 5;           // 32 n-blocks (4096/128)
    const int bn = swz & 31;

    const int tid  = threadIdx.x;
    const int w    = tid >> 6, lane = tid & 63;
    const int wr   = w >> 1,   wc   = w & 1;
    const int fr   = lane & 15, fq  = lane >> 4;

    const ushort* agbase = Ap + ((size_t)(bm * 128 + w * 32 + (lane >> 3))) * KP + (lane & 7) * 8;
    const ushort* bgbase = Bp + ((size_t)(bn * 128 + w * 32 + (lane >> 3))) * KP + (lane & 7) * 8;
    ushort* alds = &Asm[(w * 32) * 64];
    ushort* blds = &Bsm[(w * 32) * 64];

    f32x4 acc[4][4];
#pragma unroll
    for (int i = 0; i < 4; ++i)
#pragma unroll
        for (int j = 0; j < 4; ++j) acc[i][j] = (f32x4){0.f, 0.f, 0.f, 0.f};

    const bf16x8* As8 = (const bf16x8*)Asm;
    const bf16x8* Bs8 = (const bf16x8*)Bsm;
    const int aoff = (wr * 64 + fr) * 8 + fq;
    const int boff = (wc * 64 + fr) * 8 + fq;

    for (int k0 = 0; k0 < KP; k0 += 64) {
#pragma unroll
        for (int i = 0; i < 4; ++i) {
            __builtin_amdgcn_global_load_lds(
                (const __attribute__((address_space(1))) void*)(agbase + (size_t)i * 8 * KP + k0),
                (__attribute__((address_space(3))) void*)(alds + i * 8 * 64), 16, 0, 0);
            __builtin_amdgcn_global_load_lds(
                (const __attribute__((address_space(1))) void*)(bgbase + (size_t)i * 8 * KP + k0),
                (__attribute__((address_space(3))) void*)(blds + i * 8 * 64), 16, 0, 0);
        }
        __syncthreads();
#pragma unroll
        for (int kk = 0; kk < 2; ++kk) {
            bf16x8 a0 = As8[aoff + kk * 4 + 0 * 128];
            bf16x8 a1 = As8[aoff + kk * 4 + 1 * 128];
            bf16x8 a2 = As8[aoff + kk * 4 + 2 * 128];
            bf16x8 a3 = As8[aoff + kk * 4 + 3 * 128];
            bf16x8 b0 = Bs8[boff + kk * 4 + 0 * 128];
            bf16x8 b1 = Bs8[boff + kk * 4 + 1 * 128];
            bf16x8 b2 = Bs8[boff + kk * 4 + 2 * 128];
            bf16x8 b3 = Bs8[boff + kk * 4 + 3 * 128];
            acc[0][0] = __builtin_amdgcn_mfma_f32_16x16x32_bf16(a0, b0, acc[0][0], 0, 0, 0);
            acc[0][1] = __builtin_amdgcn_mfma_f32_16x16x32_bf16(a0, b1, acc[0][1], 0, 0, 0);
            acc[0][2] = __builtin_amdgcn_mfma_f32_16x16x32_bf16(a0, b2, acc[0][2], 0, 0, 0);
            acc[0][3] = __builtin_amdgcn_mfma_f32_16x16x32_bf16(a0, b3, acc[0][3], 0, 0, 0);
            acc[1][0] = __builtin_amdgcn_mfma_f32_16x16x32_bf16(a1, b0, acc[1][0], 0, 0, 0);
            acc[1][1] = __builtin_amdgcn_mfma_f32_16x16x32_bf16(a1, b1, acc[1][1], 0, 0, 0);
            acc[1][2] = __builtin_amdgcn_mfma_f32_16x16x32_bf16(a1, b2, acc[1][2], 0, 0, 0);
            acc[1][3] = __builtin_amdgcn_mfma_f32_16x16x32_bf16(a1, b3, acc[1][3], 0, 0, 0);
            acc[2][0] = __builtin_amdgcn_mfma_f32_16x16x32_bf16(a2, b0, acc[2][0], 0, 0, 0);
            acc[2][1] = __builtin_amdgcn_mfma_f32_16x16x32_bf16(a2, b1, acc[2][1], 0, 0, 0);
            acc[2][2] = __builtin_amdgcn_mfma_f32_16x16x32_bf16(a2, b2, acc[2][2], 0, 0, 0);
            acc[2][3] = __builtin_amdgcn_mfma_f32_16x16x32_bf16(a2, b3, acc[2][3], 0, 0, 0);
            acc[3][0] = __builtin_amdgcn_mfma_f32_16x16x32_bf16(a3, b0, acc[3][0], 0, 0, 0);
            acc[3][1] = __builtin_amdgcn_mfma_f32_16x16x32_bf16(a3, b1, acc[3][1], 0, 0, 0);
            acc[3][2] = __builtin_amdgcn_mfma_f32_16x16x32_bf16(a3, b2, acc[3][2], 0, 0, 0);
            acc[3][3] = __builtin_amdgcn_mfma_f32_16x16x32_bf16(a3, b3, acc[3][3], 0, 0, 0);
        }
        __syncthreads();
    }

    // C/D layout (m89-verified): col = lane&15, row = (lane>>4)*4 + reg
    const int mbase = bm * 128 + wr * 64 + fq * 4;
    const int nbase = bn * 128 + wc * 64 + fr;
#pragma unroll
    for (int i = 0; i < 4; ++i)
#pragma unroll
        for (int j = 0; j < 4; ++j)
#pragma unroll
            for (int r = 0; r < 4; ++r)
                Z[(size_t)(mbase + i * 16 + r) * HDIM + nbase + j * 16] = acc[i][j][r];
}

// ---------- Layer-1 approx IF recurrence + near-threshold flagging ----------
__global__ __launch_bounds__(256) void k_layer1_flag(const float* __restrict__ Z,
                                                     float* __restrict__ v1s,
                                                     uint64_t* __restrict__ S1,
                                                     uint64_t* __restrict__ flags,
                                                     int tbase, int first) {
    const size_t i = (size_t)blockIdx.x * 256 + threadIdx.x;
    float v = first ? 0.0f : v1s[i];
    const int lane = threadIdx.x & 63;
    const size_t word = i >> 6;
    uint64_t nearAcc = 0;
    for (int t = 0; t < TC; ++t) {
        v += Z[(size_t)t * BH + i];
        bool s    = (v >= 1.0f);
        bool near = (fabsf(v - 1.0f) < DELTA);
        unsigned long long sm = __ballot(s);
        nearAcc |= (uint64_t)__ballot(near);
        if (lane == 0) S1[(size_t)(tbase + t) * WORDS_PER_T + word] = sm;
        if (s) v = 0.0f;
    }
    if (lane == 0) flags[word] = first ? nearAcc : (flags[word] | nearAcc);
    v1s[i] = v;
}

// ---------- Exact fixup: recompute flagged (b,h) chains bitwise ----------
// Block per b. x staged in LDS 16 timesteps at a time. Each thread owns FOUR
// flagged h rows: one ascending-k pass per half, each xs read (LDS broadcast)
// feeds 16 fmas (4 h x 4 components) instead of 4 -> ~4x fewer LDS-pipe slots
// (r11 fixup was LDS-broadcast-bound at 339 us). Each z[h][t] chain receives
// its fmas in strictly ascending k -> bitwise identical to the reference.
__global__ __launch_bounds__(256) void k_fixup(const float* __restrict__ x,
                                               const float* __restrict__ W1,
                                               const uint64_t* __restrict__ flags,
                                               uint64_t* __restrict__ S1) {
    __shared__ float xs[16][788];   // [t][k], rows 16B-aligned; 50.4 KB
    __shared__ int   list[FIXLIST];
    __shared__ int   cnt;
    const int b   = blockIdx.x;
    const int tid = threadIdx.x;
    if (tid == 0) cnt = 0;
    __syncthreads();
    if (tid < 64) {
        uint64_t w = flags[b * 64 + tid];
        while (w) {
            int bit = __builtin_ctzll(w);
            w &= w - 1;
            int p = atomicAdd(&cnt, 1);
            if (p < FIXLIST) list[p] = tid * 64 + bit;
        }
    }
    __syncthreads();
    const int n = min(cnt, FIXLIST);
    if (n == 0) return;

    for (int j0 = 0; j0 < n; j0 += 1024) {   // 256 threads x 4 h each
        const int jj = j0 + tid * 4;
        const int h0 = (jj     < n) ? list[jj]     : -1;
        const int h1 = (jj + 1 < n) ? list[jj + 1] : -1;
        const int h2 = (jj + 2 < n) ? list[jj + 2] : -1;
        const int h3 = (jj + 3 < n) ? list[jj + 3] : -1;
        const float* wr0 = W1 + (size_t)(h0 >= 0 ? h0 : 0) * INDIM;
        const float* wr1 = W1 + (size_t)(h1 >= 0 ? h1 : 0) * INDIM;
        const float* wr2 = W1 + (size_t)(h2 >= 0 ? h2 : 0) * INDIM;
        const float* wr3 = W1 + (size_t)(h3 >= 0 ? h3 : 0) * INDIM;
        float v0 = 0.0f, v1 = 0.0f, v2 = 0.0f, v3 = 0.0f;
        for (int half = 0; half < 2; ++half) {
            __syncthreads();   // previous pass done reading xs
            for (int idx = tid; idx < 16 * 196; idx += 256) {
                int t  = idx / 196;
                int kq = (idx % 196) * 4;
                *(float4*)&xs[t][kq] =
                    *(const float4*)(x + ((size_t)(half * 16 + t) * BATCH + b) * INDIM + kq);
            }
            __syncthreads();
            if (h0 >= 0) {   // list is packed: h0<0 implies all four invalid
                float z0[16], z1[16], z2[16], z3[16];
#pragma unroll
                for (int t = 0; t < 16; ++t) { z0[t] = 0.f; z1[t] = 0.f; z2[t] = 0.f; z3[t] = 0.f; }
                for (int kq = 0; kq < INDIM; kq += 4) {
                    float4 a0 = *(const float4*)(wr0 + kq);
                    float4 a1 = *(const float4*)(wr1 + kq);
                    float4 a2 = *(const float4*)(wr2 + kq);
                    float4 a3 = *(const float4*)(wr3 + kq);
#pragma unroll
                    for (int t = 0; t < 16; ++t) {
                        float4 xv = *(const float4*)&xs[t][kq];   // LDS broadcast, reused 4x
                        z0[t] = fmaf(xv.x, a0.x, z0[t]);
                        z0[t] = fmaf(xv.y, a0.y, z0[t]);
                        z0[t] = fmaf(xv.z, a0.z, z0[t]);
                        z0[t] = fmaf(xv.w, a0.w, z0[t]);
                        z1[t] = fmaf(xv.x, a1.x, z1[t]);
                        z1[t] = fmaf(xv.y, a1.y, z1[t]);
                        z1[t] = fmaf(xv.z, a1.z, z1[t]);
                        z1[t] = fmaf(xv.w, a1.w, z1[t]);
                        z2[t] = fmaf(xv.x, a2.x, z2[t]);
                        z2[t] = fmaf(xv.y, a2.y, z2[t]);
                        z2[t] = fmaf(xv.z, a2.z, z2[t]);
                        z2[t] = fmaf(xv.w, a2.w, z2[t]);
                        z3[t] = fmaf(xv.x, a3.x, z3[t]);
                        z3[t] = fmaf(xv.y, a3.y, z3[t]);
                        z3[t] = fmaf(xv.z, a3.z, z3[t]);
                        z3[t] = fmaf(xv.w, a3.w, z3[t]);
                    }
                }
#pragma unroll
                for (int t = 0; t < 16; ++t) {
                    const size_t wbase = (size_t)(half * 16 + t) * WORDS_PER_T + (size_t)b * 64;
                    {
                        v0 += z0[t];
                        bool s = (v0 >= 1.0f);
                        unsigned long long* wp = (unsigned long long*)&S1[wbase + (h0 >> 6)];
                        unsigned long long m = 1ull << (h0 & 63);
                        if (s) { atomicOr(wp, m); v0 = 0.0f; } else { atomicAnd(wp, ~m); }
                    }
                    if (h1 >= 0) {
                        v1 += z1[t];
                        bool s = (v1 >= 1.0f);
                        unsigned long long* wp = (unsigned long long*)&S1[wbase + (h1 >> 6)];
                        unsigned long long m = 1ull << (h1 & 63);
                        if (s) { atomicOr(wp, m); v1 = 0.0f; } else { atomicAnd(wp, ~m); }
                    }
                    if (h2 >= 0) {
                        v2 += z2[t];
                        bool s = (v2 >= 1.0f);
                        unsigned long long* wp = (unsigned long long*)&S1[wbase + (h2 >> 6)];
                        unsigned long long m = 1ull << (h2 & 63);
                        if (s) { atomicOr(wp, m); v2 = 0.0f; } else { atomicAnd(wp, ~m); }
                    }
                    if (h3 >= 0) {
                        v3 += z3[t];
                        bool s = (v3 >= 1.0f);
                        unsigned long long* wp = (unsigned long long*)&S1[wbase + (h3 >> 6)];
                        unsigned long long m = 1ull << (h3 & 63);
                        if (s) { atomicOr(wp, m); v3 = 0.0f; } else { atomicAnd(wp, ~m); }
                    }
                }
            }
        }
    }
}

// ---------- Layer-2 partial sums from spike bitmask ----------
__global__ __launch_bounds__(256) void k_layer2_partial(const uint64_t* __restrict__ S1,
                                                        const float* __restrict__ W2T,
                                                        float* __restrict__ part,
                                                        int rowsTotal) {
    __shared__ float w[1024][10];   // 40 KB
    const int hs = blockIdx.y;
    for (int i = threadIdx.x; i < 1024 * 10; i += 256)
        w[i / 10][i % 10] = W2T[hs * 1024 * 10 + i];
    __syncthreads();

    const int row = blockIdx.x * 256 + threadIdx.x;
    const uint64_t* wp = S1 + (size_t)row * 64 + hs * 16;
    float acc[10] = {};
    for (int wi = 0; wi < 16; ++wi) {
        uint64_t m = wp[wi];
        while (m) {
            int bit = __builtin_ctzll(m);
            m &= m - 1;
            int hl = wi * 64 + bit;
#pragma unroll
            for (int o = 0; o < 10; ++o) acc[o] += w[hl][o];
        }
    }
    float* p = part + ((size_t)hs * rowsTotal + row) * 10;
#pragma unroll
    for (int o = 0; o < 10; ++o) p[o] = acc[o];
}

// ---------- Layer-2 IF recurrence + spike record ----------
__global__ __launch_bounds__(256) void k_layer2_rec(const float* __restrict__ part,
                                                    float* __restrict__ out) {
    const int i = blockIdx.x * 256 + threadIdx.x;
    if (i >= BATCH * OUTDIM) return;
    float v = 0.0f, rec = 0.0f;
    const int rowsTotal = T_TOTAL * BATCH;
    const int b = i / OUTDIM, o = i % OUTDIM;
    for (int t = 0; t < T_TOTAL; ++t) {
        const int r = t * BATCH + b;
        float sig = 0.0f;
#pragma unroll
        for (int hs = 0; hs < 4; ++hs)
            sig += part[((size_t)hs * rowsTotal + r) * 10 + o];
        v += sig;
        bool s = (v >= 1.0f);
        rec += s ? 1.0f : 0.0f;
        if (s) v = 0.0f;
    }
    out[i] = rec;
}

// ---------- launch ----------
extern "C" void kernel_launch(void* const* d_in, const int* in_sizes, int n_in,
                              void* d_out, int out_size, void* d_ws, size_t ws_size,
                              hipStream_t stream) {
    (void)in_sizes; (void)n_in; (void)out_size; (void)ws_size;
    const float* x  = (const float*)d_in[0];   // [32][1024][784]
    const float* W1 = (const float*)d_in[1];   // [4096][784]
    const float* W2 = (const float*)d_in[2];   // [10][4096]
    float* out = (float*)d_out;                // [1024][10]

    // ws layout (total ~230 MB)
    char* p = (char*)d_ws;
    float*    W2T   = (float*)p;    p += (size_t)HDIM * OUTDIM * 4;        // 160 KB
    float*    v1s   = (float*)p;    p += (size_t)BH * 4;                   // 16.8 MB
    ushort*   Bp    = (ushort*)p;   p += (size_t)HDIM * KP * 2;            // 19.4 MB
    ushort*   Ap    = (ushort*)p;   p += (size_t)MC * KP * 2;              // 38.8 MB
    float*    Z     = (float*)p;    p += (size_t)TC * BH * 4;              // 134.2 MB
    uint64_t* S1    = (uint64_t*)p; p += (size_t)T_TOTAL * WORDS_PER_T * 8;// 16.8 MB
    uint64_t* flags = (uint64_t*)p; p += (size_t)WORDS_PER_T * 8;          // 0.5 MB
    float*    part  = (float*)p;                                           // 5.2 MB

    k_transpose_w2<<<(HDIM * OUTDIM + 255) / 256, 256, 0, stream>>>(W2, W2T);
    k_split3<<<(HDIM * 400 + 255) / 256, 256, 0, stream>>>(W1, Bp, HDIM, 0);

    const int nch = T_TOTAL / TC;   // 4
    for (int c = 0; c < nch; ++c) {
        const float* xc = x + (size_t)c * MC * INDIM;
        k_split3<<<(MC * 400 + 255) / 256, 256, 0, stream>>>(xc, Ap, MC, 1);
        k_gemm_bf16<<<(MC / 128) * 32, 256, 0, stream>>>(Ap, Bp, Z);
        k_layer1_flag<<<BH / 256, 256, 0, stream>>>(Z, v1s, S1, flags, c * TC, c == 0);
    }
    k_fixup<<<BATCH, 256, 0, stream>>>(x, W1, flags, S1);
    k_layer2_partial<<<dim3(T_TOTAL * BATCH / 256, 4), 256, 0, stream>>>(
        S1, W2T, part, T_TOTAL * BATCH);
    k_layer2_rec<<<(BATCH * OUTDIM + 255) / 256, 256, 0, stream>>>(part, out);
}

// Round 13
// 1313.547 us; speedup vs baseline: 1.3152x; 1.3152x over previous
//
#include <hip/hip_runtime.h>
#include <stdint.h>

typedef __attribute__((ext_vector_type(8))) short bf16x8;
typedef __attribute__((ext_vector_type(4))) float f32x4;

#define T_TOTAL 32
#define BATCH   1024
#define INDIM   784
#define HDIM    4096
#define OUTDIM  10
#define BH      (BATCH * HDIM)      // 4,194,304
#define WORDS_PER_T (BH / 64)       // 65,536 u64 words per timestep
#define TC      8                   // timesteps per GEMM chunk
#define MC      (TC * BATCH)        // 8192 rows per chunk
// concat-K layout (small-magnitude segments first, hh LAST):
// [0,784)=hm [784,1568)=mh [1568,2352)=hh [2352,2368)=0
#define KP      2368                // 74 * 32
#define NT      74                  // K-tiles of 32
#define DELTA   2e-3f               // near-threshold flag window (proven r9-r12)
#define FIXLIST 3072

// ---------- 2-way bf16 truncation split: a = h + m + residual(~2^-16) ----------
__device__ __forceinline__ void split2(float a, ushort& h, ushort& m) {
    unsigned ua = __float_as_uint(a);
    h = (ushort)(ua >> 16);
    float r = a - __uint_as_float(ua & 0xFFFF0000u);   // exact
    m = (ushort)(__float_as_uint(r) >> 16);
}

// ---------- split fp32 [R][784] into concat-K bf16 [R][2368] ----------
__global__ __launch_bounds__(256) void k_split3(const float* __restrict__ src,
                                                ushort* __restrict__ dst,
                                                int R, int isA) {
    int idx = blockIdx.x * 256 + threadIdx.x;
    int main_n = R * 392;                       // 784/2 pairs per row
    if (idx < main_n) {
        int row = idx / 392, kk = (idx % 392) * 2;
        float a0 = src[(size_t)row * INDIM + kk];
        float a1 = src[(size_t)row * INDIM + kk + 1];
        ushort h0, m0, h1, m1;
        split2(a0, h0, m0);
        split2(a1, h1, m1);
        ushort2 H; H.x = h0; H.y = h1;
        ushort2 M; M.x = m0; M.y = m1;
        ushort2 s1 = isA ? H : M;   // hm: A=h, B=m
        ushort2 s2 = isA ? M : H;   // mh: A=m, B=h
        ushort* d = dst + (size_t)row * KP;
        *(ushort2*)(d + kk)        = s1;  // hm
        *(ushort2*)(d + 784 + kk)  = s2;  // mh
        *(ushort2*)(d + 1568 + kk) = H;   // hh (accumulated last)
    } else if (idx < main_n + R * 8) {
        int j = idx - main_n;
        int row = j / 8, q = j % 8;
        ushort2 z; z.x = 0; z.y = 0;
        *(ushort2*)(dst + (size_t)row * KP + 2352 + q * 2) = z;
    }
}

// ---------- W2 transpose: W2[10][4096] -> W2T[4096][10] ----------
__global__ void k_transpose_w2(const float* __restrict__ W2, float* __restrict__ W2T) {
    int i = blockIdx.x * 256 + threadIdx.x;
    if (i < HDIM * OUTDIM) {
        int h = i / OUTDIM, o = i % OUTDIM;
        W2T[i] = W2[o * HDIM + h];
    }
}

// ---------- bf16 MFMA GEMM, pipelined (T3+T4+T5): 256x256 tile, BK=32 ----------
// 512 threads = 8 waves (2m x 4n), per-wave C = 128x64 (8x4 frags of 16x16x32).
// Double-buffered LDS (slot = t&1, 64 KB), raw s_barrier + counted vmcnt(2):
//   tile t: [vmcnt(2); barrier] P0{read FA[0..7],FB[0..1]; issue B(t+1)->s^1; 16 MFMA}
//           [barrier] P1{issue A(t+2)->s; read FB[2..3]; 16 MFMA}
// Race-free: A-reads of slot s all in P0 (before mid barrier); B(t+1) targets the
// other slot whose readers preceded the top barrier. vmcnt(2) leaves A(t+1)'s 2
// issues in flight (never drains the pipe); vmcnt(0) only at the final tile.
// BK=32 rows (64 B) are bank-conflict-free unswizzled: bank = (frParity*16+fq*4),
// 64 lanes spread uniformly over 32 banks -> hardware minimum cycles.
__global__ __launch_bounds__(512) void k_gemm_bf16(const ushort* __restrict__ Ap,
                                                   const ushort* __restrict__ Bp,
                                                   float* __restrict__ Z) {
    __shared__ ushort Asm[2][256 * 32];   // 2 x 16 KB
    __shared__ ushort Bsm[2][256 * 32];   // 2 x 16 KB

    // XCD-bijective swizzle (gridDim.x = 512, % 8 == 0)
    const int cpx = gridDim.x >> 3;
    const int swz = (blockIdx.x & 7) * cpx + (blockIdx.x >> 3);
    const int bm  = swz >> 4;            // 32 m-blocks (MC/256)
    const int bn  = swz & 15;            // 16 n-blocks (HDIM/256)

    const int tid  = threadIdx.x;
    const int wid  = tid >> 6, lane = tid & 63;
    const int wm   = wid >> 2, wn = wid & 3;
    const int fr   = lane & 15, fq = lane >> 4;

    // staging: per issue (128 rows x 32 k = 8 KB), thread -> row tid>>2, k (tid&3)*8
    const int srow  = tid >> 2;           // 0..127
    const int skcol = (tid & 3) << 3;     // 0,8,16,24
    const ushort* agb = Ap + (size_t)(bm * 256 + srow) * KP + skcol;
    const ushort* bgb = Bp + (size_t)(bn * 256 + srow) * KP + skcol;
    const int sbase = wid * 16 * 32;      // wave-uniform LDS base (elements)

#define STAGE_A(t, s) do {                                                            \
    __builtin_amdgcn_global_load_lds(                                                 \
        (const __attribute__((address_space(1))) void*)(agb + (size_t)(t) * 32),      \
        (__attribute__((address_space(3))) void*)(&Asm[s][sbase]), 16, 0, 0);         \
    __builtin_amdgcn_global_load_lds(                                                 \
        (const __attribute__((address_space(1))) void*)(agb + (size_t)(t) * 32 + (size_t)128 * KP), \
        (__attribute__((address_space(3))) void*)(&Asm[s][4096 + sbase]), 16, 0, 0);  \
} while (0)
#define STAGE_B(t, s) do {                                                            \
    __builtin_amdgcn_global_load_lds(                                                 \
        (const __attribute__((address_space(1))) void*)(bgb + (size_t)(t) * 32),      \
        (__attribute__((address_space(3))) void*)(&Bsm[s][sbase]), 16, 0, 0);         \
    __builtin_amdgcn_global_load_lds(                                                 \
        (const __attribute__((address_space(1))) void*)(bgb + (size_t)(t) * 32 + (size_t)128 * KP), \
        (__attribute__((address_space(3))) void*)(&Bsm[s][4096 + sbase]), 16, 0, 0);  \
} while (0)

    f32x4 acc[8][4];
#pragma unroll
    for (int i = 0; i < 8; ++i)
#pragma unroll
        for (int j = 0; j < 4; ++j) acc[i][j] = (f32x4){0.f, 0.f, 0.f, 0.f};

    const int aidx = (wm * 128 + fr) * 4 + fq;   // + i*64
    const int bidx = (wn * 64 + fr) * 4 + fq;    // + j*64

    // prologue: A(0),B(0) -> slot0; A(1) -> slot1  (6 issues outstanding)
    STAGE_A(0, 0);
    STAGE_B(0, 0);
    STAGE_A(1, 1);

    for (int t = 0; t < NT; ++t) {
        const int s = t & 1;
        if (t == NT - 1) asm volatile("s_waitcnt vmcnt(0)" ::: "memory");
        else             asm volatile("s_waitcnt vmcnt(2)" ::: "memory");
        __builtin_amdgcn_s_barrier();

        const bf16x8* A8 = (const bf16x8*)Asm[s];
        const bf16x8* B8 = (const bf16x8*)Bsm[s];

        // ---- P0 ----
        bf16x8 fa[8];
#pragma unroll
        for (int i = 0; i < 8; ++i) fa[i] = A8[aidx + i * 64];
        bf16x8 fb0 = B8[bidx];
        bf16x8 fb1 = B8[bidx + 64];
        if (t + 1 < NT) STAGE_B(t + 1, s ^ 1);
        __builtin_amdgcn_s_setprio(1);
#pragma unroll
        for (int i = 0; i < 8; ++i) {
            acc[i][0] = __builtin_amdgcn_mfma_f32_16x16x32_bf16(fa[i], fb0, acc[i][0], 0, 0, 0);
            acc[i][1] = __builtin_amdgcn_mfma_f32_16x16x32_bf16(fa[i], fb1, acc[i][1], 0, 0, 0);
        }
        __builtin_amdgcn_s_setprio(0);

        // ---- P1 ----
        __builtin_amdgcn_s_barrier();         // all P0 A-reads issued before A-overwrite
        if (t + 2 < NT) STAGE_A(t + 2, s);
        bf16x8 fb2 = B8[bidx + 128];
        bf16x8 fb3 = B8[bidx + 192];
        __builtin_amdgcn_s_setprio(1);
#pragma unroll
        for (int i = 0; i < 8; ++i) {
            acc[i][2] = __builtin_amdgcn_mfma_f32_16x16x32_bf16(fa[i], fb2, acc[i][2], 0, 0, 0);
            acc[i][3] = __builtin_amdgcn_mfma_f32_16x16x32_bf16(fa[i], fb3, acc[i][3], 0, 0, 0);
        }
        __builtin_amdgcn_s_setprio(0);
    }

    // C/D layout (m89-verified): col = lane&15, row = (lane>>4)*4 + reg
    const int m0 = bm * 256 + wm * 128 + fq * 4;
    const int n0 = bn * 256 + wn * 64 + fr;
#pragma unroll
    for (int i = 0; i < 8; ++i)
#pragma unroll
        for (int j = 0; j < 4; ++j)
#pragma unroll
            for (int r = 0; r < 4; ++r)
                Z[(size_t)(m0 + i * 16 + r) * HDIM + n0 + j * 16] = acc[i][j][r];
#undef STAGE_A
#undef STAGE_B
}

// ---------- Layer-1 approx IF recurrence + near-threshold flagging ----------
__global__ __launch_bounds__(256) void k_layer1_flag(const float* __restrict__ Z,
                                                     float* __restrict__ v1s,
                                                     uint64_t* __restrict__ S1,
                                                     uint64_t* __restrict__ flags,
                                                     int tbase, int first) {
    const size_t i = (size_t)blockIdx.x * 256 + threadIdx.x;
    float v = first ? 0.0f : v1s[i];
    const int lane = threadIdx.x & 63;
    const size_t word = i >> 6;
    uint64_t nearAcc = 0;
    for (int t = 0; t < TC; ++t) {
        v += Z[(size_t)t * BH + i];
        bool s    = (v >= 1.0f);
        bool near = (fabsf(v - 1.0f) < DELTA);
        unsigned long long sm = __ballot(s);
        nearAcc |= (uint64_t)__ballot(near);
        if (lane == 0) S1[(size_t)(tbase + t) * WORDS_PER_T + word] = sm;
        if (s) v = 0.0f;
    }
    if (lane == 0) flags[word] = first ? nearAcc : (flags[word] | nearAcc);
    v1s[i] = v;
}

// ---------- Exact fixup (r11 version): recompute flagged (b,h) chains bitwise ----------
// Block per b. x staged in LDS 16 timesteps at a time; each flagged-h thread
// makes ONE ascending-k pass over its W1 row (float4), updating 16 independent
// z[t] accumulators per k (16-way ILP; each z[t] chain is ascending-k fma ->
// bitwise identical to the reference). v carried across the two half-passes.
__global__ __launch_bounds__(256) void k_fixup(const float* __restrict__ x,
                                               const float* __restrict__ W1,
                                               const uint64_t* __restrict__ flags,
                                               uint64_t* __restrict__ S1) {
    __shared__ float xs[16][788];   // [t][k], rows 16B-aligned; 50.4 KB
    __shared__ int   list[FIXLIST];
    __shared__ int   cnt;
    const int b   = blockIdx.x;
    const int tid = threadIdx.x;
    if (tid == 0) cnt = 0;
    __syncthreads();
    if (tid < 64) {
        uint64_t w = flags[b * 64 + tid];
        while (w) {
            int bit = __builtin_ctzll(w);
            w &= w - 1;
            int p = atomicAdd(&cnt, 1);
            if (p < FIXLIST) list[p] = tid * 64 + bit;
        }
    }
    __syncthreads();
    const int n = min(cnt, FIXLIST);
    if (n == 0) return;

    for (int j0 = 0; j0 < n; j0 += 256) {
        const int j = j0 + tid;
        const int h = (j < n) ? list[j] : -1;
        const float* wrow = W1 + (size_t)(h >= 0 ? h : 0) * INDIM;
        float v = 0.0f;
        for (int half = 0; half < 2; ++half) {
            __syncthreads();   // previous pass done reading xs
            for (int idx = tid; idx < 16 * 196; idx += 256) {
                int t  = idx / 196;
                int kq = (idx % 196) * 4;
                *(float4*)&xs[t][kq] =
                    *(const float4*)(x + ((size_t)(half * 16 + t) * BATCH + b) * INDIM + kq);
            }
            __syncthreads();
            if (h >= 0) {
                float z[16];
#pragma unroll
                for (int t = 0; t < 16; ++t) z[t] = 0.0f;
                for (int kq = 0; kq < INDIM; kq += 4) {
                    float4 w4 = *(const float4*)(wrow + kq);
#pragma unroll
                    for (int t = 0; t < 16; ++t) {
                        float4 xv = *(const float4*)&xs[t][kq];   // wave-broadcast reads
                        z[t] = fmaf(xv.x, w4.x, z[t]);
                        z[t] = fmaf(xv.y, w4.y, z[t]);
                        z[t] = fmaf(xv.z, w4.z, z[t]);
                        z[t] = fmaf(xv.w, w4.w, z[t]);
                    }
                }
#pragma unroll
                for (int t = 0; t < 16; ++t) {
                    v += z[t];
                    bool s = (v >= 1.0f);
                    unsigned long long* wp = (unsigned long long*)
                        &S1[(size_t)(half * 16 + t) * WORDS_PER_T + (size_t)b * 64 + (h >> 6)];
                    unsigned long long m = 1ull << (h & 63);
                    if (s) { atomicOr(wp, m); v = 0.0f; }
                    else   { atomicAnd(wp, ~m); }
                }
            }
        }
    }
}

// ---------- Layer-2 partial sums from spike bitmask ----------
__global__ __launch_bounds__(256) void k_layer2_partial(const uint64_t* __restrict__ S1,
                                                        const float* __restrict__ W2T,
                                                        float* __restrict__ part,
                                                        int rowsTotal) {
    __shared__ float w[1024][10];   // 40 KB
    const int hs = blockIdx.y;
    for (int i = threadIdx.x; i < 1024 * 10; i += 256)
        w[i / 10][i % 10] = W2T[hs * 1024 * 10 + i];
    __syncthreads();

    const int row = blockIdx.x * 256 + threadIdx.x;
    const uint64_t* wp = S1 + (size_t)row * 64 + hs * 16;
    float acc[10] = {};
    for (int wi = 0; wi < 16; ++wi) {
        uint64_t m = wp[wi];
        while (m) {
            int bit = __builtin_ctzll(m);
            m &= m - 1;
            int hl = wi * 64 + bit;
#pragma unroll
            for (int o = 0; o < 10; ++o) acc[o] += w[hl][o];
        }
    }
    float* p = part + ((size_t)hs * rowsTotal + row) * 10;
#pragma unroll
    for (int o = 0; o < 10; ++o) p[o] = acc[o];
}

// ---------- Layer-2 IF recurrence + spike record ----------
__global__ __launch_bounds__(256) void k_layer2_rec(const float* __restrict__ part,
                                                    float* __restrict__ out) {
    const int i = blockIdx.x * 256 + threadIdx.x;
    if (i >= BATCH * OUTDIM) return;
    float v = 0.0f, rec = 0.0f;
    const int rowsTotal = T_TOTAL * BATCH;
    const int b = i / OUTDIM, o = i % OUTDIM;
    for (int t = 0; t < T_TOTAL; ++t) {
        const int r = t * BATCH + b;
        float sig = 0.0f;
#pragma unroll
        for (int hs = 0; hs < 4; ++hs)
            sig += part[((size_t)hs * rowsTotal + r) * 10 + o];
        v += sig;
        bool s = (v >= 1.0f);
        rec += s ? 1.0f : 0.0f;
        if (s) v = 0.0f;
    }
    out[i] = rec;
}

// ---------- launch ----------
extern "C" void kernel_launch(void* const* d_in, const int* in_sizes, int n_in,
                              void* d_out, int out_size, void* d_ws, size_t ws_size,
                              hipStream_t stream) {
    (void)in_sizes; (void)n_in; (void)out_size; (void)ws_size;
    const float* x  = (const float*)d_in[0];   // [32][1024][784]
    const float* W1 = (const float*)d_in[1];   // [4096][784]
    const float* W2 = (const float*)d_in[2];   // [10][4096]
    float* out = (float*)d_out;                // [1024][10]

    // ws layout (total ~230 MB)
    char* p = (char*)d_ws;
    float*    W2T   = (float*)p;    p += (size_t)HDIM * OUTDIM * 4;        // 160 KB
    float*    v1s   = (float*)p;    p += (size_t)BH * 4;                   // 16.8 MB
    ushort*   Bp    = (ushort*)p;   p += (size_t)HDIM * KP * 2;            // 19.4 MB
    ushort*   Ap    = (ushort*)p;   p += (size_t)MC * KP * 2;              // 38.8 MB
    float*    Z     = (float*)p;    p += (size_t)TC * BH * 4;              // 134.2 MB
    uint64_t* S1    = (uint64_t*)p; p += (size_t)T_TOTAL * WORDS_PER_T * 8;// 16.8 MB
    uint64_t* flags = (uint64_t*)p; p += (size_t)WORDS_PER_T * 8;          // 0.5 MB
    float*    part  = (float*)p;                                           // 5.2 MB

    k_transpose_w2<<<(HDIM * OUTDIM + 255) / 256, 256, 0, stream>>>(W2, W2T);
    k_split3<<<(HDIM * 400 + 255) / 256, 256, 0, stream>>>(W1, Bp, HDIM, 0);

    const int nch = T_TOTAL / TC;   // 4
    for (int c = 0; c < nch; ++c) {
        const float* xc = x + (size_t)c * MC * INDIM;
        k_split3<<<(MC * 400 + 255) / 256, 256, 0, stream>>>(xc, Ap, MC, 1);
        k_gemm_bf16<<<(MC / 256) * (HDIM / 256), 512, 0, stream>>>(Ap, Bp, Z);
        k_layer1_flag<<<BH / 256, 256, 0, stream>>>(Z, v1s, S1, flags, c * TC, c == 0);
    }
    k_fixup<<<BATCH, 256, 0, stream>>>(x, W1, flags, S1);
    k_layer2_partial<<<dim3(T_TOTAL * BATCH / 256, 4), 256, 0, stream>>>(
        S1, W2T, part, T_TOTAL * BATCH);
    k_layer2_rec<<<(BATCH * OUTDIM + 255) / 256, 256, 0, stream>>>(part, out);
}

// Round 14
// 1237.556 us; speedup vs baseline: 1.3959x; 1.0614x over previous
//
#include <hip/hip_runtime.h>
#include <stdint.h>

typedef __attribute__((ext_vector_type(8))) short bf16x8;
typedef __attribute__((ext_vector_type(4))) float f32x4;

#define T_TOTAL 32
#define BATCH   1024
#define INDIM   784
#define HDIM    4096
#define OUTDIM  10
#define BH      (BATCH * HDIM)      // 4,194,304
#define WORDS_PER_T (BH / 64)       // 65,536 u64 words per timestep
#define TC      8                   // timesteps per GEMM chunk
#define MC      (TC * BATCH)        // 8192 rows per chunk
// concat-K layout (small-magnitude segments first, hh LAST):
// [0,784)=hm [784,1568)=mh [1568,2352)=hh [2352,2368)=0
#define KP      2368                // 74 * 32
#define NT      74                  // K-tiles of 32
// Near-threshold flag window. Error model: dropped terms (mm + l-residuals,
// 2352 bounded iid random-sign terms) give z-err rms ~1.2e-5, run-accumulated
// <~4e-5; Hoeffding P(|v_err|>5e-4) has exponent >>10 -> 0 expected misses
// over 1.3e8 decisions. r9-r13 passed at 2e-3; 5e-4 quarters the flag count
// -> 1 active fixup wave/block instead of 4 (fixup is LDS-pipe-bound, r11/r12).
#define DELTA   5e-4f
#define FIXLIST 3072

// ---------- 2-way bf16 truncation split: a = h + m + residual(~2^-16) ----------
__device__ __forceinline__ void split2(float a, ushort& h, ushort& m) {
    unsigned ua = __float_as_uint(a);
    h = (ushort)(ua >> 16);
    float r = a - __uint_as_float(ua & 0xFFFF0000u);   // exact
    m = (ushort)(__float_as_uint(r) >> 16);
}

// ---------- split fp32 [R][784] into concat-K bf16 [R][2368] ----------
__global__ __launch_bounds__(256) void k_split3(const float* __restrict__ src,
                                                ushort* __restrict__ dst,
                                                int R, int isA) {
    int idx = blockIdx.x * 256 + threadIdx.x;
    int main_n = R * 392;                       // 784/2 pairs per row
    if (idx < main_n) {
        int row = idx / 392, kk = (idx % 392) * 2;
        float a0 = src[(size_t)row * INDIM + kk];
        float a1 = src[(size_t)row * INDIM + kk + 1];
        ushort h0, m0, h1, m1;
        split2(a0, h0, m0);
        split2(a1, h1, m1);
        ushort2 H; H.x = h0; H.y = h1;
        ushort2 M; M.x = m0; M.y = m1;
        ushort2 s1 = isA ? H : M;   // hm: A=h, B=m
        ushort2 s2 = isA ? M : H;   // mh: A=m, B=h
        ushort* d = dst + (size_t)row * KP;
        *(ushort2*)(d + kk)        = s1;  // hm
        *(ushort2*)(d + 784 + kk)  = s2;  // mh
        *(ushort2*)(d + 1568 + kk) = H;   // hh (accumulated last)
    } else if (idx < main_n + R * 8) {
        int j = idx - main_n;
        int row = j / 8, q = j % 8;
        ushort2 z; z.x = 0; z.y = 0;
        *(ushort2*)(dst + (size_t)row * KP + 2352 + q * 2) = z;
    }
}

// ---------- W2 transpose: W2[10][4096] -> W2T[4096][10] ----------
__global__ void k_transpose_w2(const float* __restrict__ W2, float* __restrict__ W2T) {
    int i = blockIdx.x * 256 + threadIdx.x;
    if (i < HDIM * OUTDIM) {
        int h = i / OUTDIM, o = i % OUTDIM;
        W2T[i] = W2[o * HDIM + h];
    }
}

// ---------- bf16 MFMA GEMM, pipelined (T3+T4+T5): 256x256 tile, BK=32 ----------
// (r13-verified: 1313us total, absmax 0.0, ~840 TF) 512 thr = 8 waves (2m x 4n).
// Double-buffered LDS (slot = t&1, 64 KB), raw s_barrier + counted vmcnt(2):
//   tile t: [vmcnt(2); barrier] P0{read FA[0..7],FB[0..1]; issue B(t+1)->s^1; 16 MFMA}
//           [barrier] P1{issue A(t+2)->s; read FB[2..3]; 16 MFMA}
__global__ __launch_bounds__(512) void k_gemm_bf16(const ushort* __restrict__ Ap,
                                                   const ushort* __restrict__ Bp,
                                                   float* __restrict__ Z) {
    __shared__ ushort Asm[2][256 * 32];   // 2 x 16 KB
    __shared__ ushort Bsm[2][256 * 32];   // 2 x 16 KB

    // XCD-bijective swizzle (gridDim.x = 512, % 8 == 0)
    const int cpx = gridDim.x >> 3;
    const int swz = (blockIdx.x & 7) * cpx + (blockIdx.x >> 3);
    const int bm  = swz >> 4;            // 32 m-blocks (MC/256)
    const int bn  = swz & 15;            // 16 n-blocks (HDIM/256)

    const int tid  = threadIdx.x;
    const int wid  = tid >> 6, lane = tid & 63;
    const int wm   = wid >> 2, wn = wid & 3;
    const int fr   = lane & 15, fq = lane >> 4;

    const int srow  = tid >> 2;           // 0..127
    const int skcol = (tid & 3) << 3;     // 0,8,16,24
    const ushort* agb = Ap + (size_t)(bm * 256 + srow) * KP + skcol;
    const ushort* bgb = Bp + (size_t)(bn * 256 + srow) * KP + skcol;
    const int sbase = wid * 16 * 32;      // wave-uniform LDS base (elements)

#define STAGE_A(t, s) do {                                                            \
    __builtin_amdgcn_global_load_lds(                                                 \
        (const __attribute__((address_space(1))) void*)(agb + (size_t)(t) * 32),      \
        (__attribute__((address_space(3))) void*)(&Asm[s][sbase]), 16, 0, 0);         \
    __builtin_amdgcn_global_load_lds(                                                 \
        (const __attribute__((address_space(1))) void*)(agb + (size_t)(t) * 32 + (size_t)128 * KP), \
        (__attribute__((address_space(3))) void*)(&Asm[s][4096 + sbase]), 16, 0, 0);  \
} while (0)
#define STAGE_B(t, s) do {                                                            \
    __builtin_amdgcn_global_load_lds(                                                 \
        (const __attribute__((address_space(1))) void*)(bgb + (size_t)(t) * 32),      \
        (__attribute__((address_space(3))) void*)(&Bsm[s][sbase]), 16, 0, 0);         \
    __builtin_amdgcn_global_load_lds(                                                 \
        (const __attribute__((address_space(1))) void*)(bgb + (size_t)(t) * 32 + (size_t)128 * KP), \
        (__attribute__((address_space(3))) void*)(&Bsm[s][4096 + sbase]), 16, 0, 0);  \
} while (0)

    f32x4 acc[8][4];
#pragma unroll
    for (int i = 0; i < 8; ++i)
#pragma unroll
        for (int j = 0; j < 4; ++j) acc[i][j] = (f32x4){0.f, 0.f, 0.f, 0.f};

    const int aidx = (wm * 128 + fr) * 4 + fq;   // + i*64
    const int bidx = (wn * 64 + fr) * 4 + fq;    // + j*64

    // prologue: A(0),B(0) -> slot0; A(1) -> slot1  (6 issues outstanding)
    STAGE_A(0, 0);
    STAGE_B(0, 0);
    STAGE_A(1, 1);

    for (int t = 0; t < NT; ++t) {
        const int s = t & 1;
        if (t == NT - 1) asm volatile("s_waitcnt vmcnt(0)" ::: "memory");
        else             asm volatile("s_waitcnt vmcnt(2)" ::: "memory");
        __builtin_amdgcn_s_barrier();

        const bf16x8* A8 = (const bf16x8*)Asm[s];
        const bf16x8* B8 = (const bf16x8*)Bsm[s];

        // ---- P0 ----
        bf16x8 fa[8];
#pragma unroll
        for (int i = 0; i < 8; ++i) fa[i] = A8[aidx + i * 64];
        bf16x8 fb0 = B8[bidx];
        bf16x8 fb1 = B8[bidx + 64];
        if (t + 1 < NT) STAGE_B(t + 1, s ^ 1);
        __builtin_amdgcn_s_setprio(1);
#pragma unroll
        for (int i = 0; i < 8; ++i) {
            acc[i][0] = __builtin_amdgcn_mfma_f32_16x16x32_bf16(fa[i], fb0, acc[i][0], 0, 0, 0);
            acc[i][1] = __builtin_amdgcn_mfma_f32_16x16x32_bf16(fa[i], fb1, acc[i][1], 0, 0, 0);
        }
        __builtin_amdgcn_s_setprio(0);

        // ---- P1 ----
        __builtin_amdgcn_s_barrier();         // all P0 A-reads issued before A-overwrite
        if (t + 2 < NT) STAGE_A(t + 2, s);
        bf16x8 fb2 = B8[bidx + 128];
        bf16x8 fb3 = B8[bidx + 192];
        __builtin_amdgcn_s_setprio(1);
#pragma unroll
        for (int i = 0; i < 8; ++i) {
            acc[i][2] = __builtin_amdgcn_mfma_f32_16x16x32_bf16(fa[i], fb2, acc[i][2], 0, 0, 0);
            acc[i][3] = __builtin_amdgcn_mfma_f32_16x16x32_bf16(fa[i], fb3, acc[i][3], 0, 0, 0);
        }
        __builtin_amdgcn_s_setprio(0);
    }

    // C/D layout (m89-verified): col = lane&15, row = (lane>>4)*4 + reg
    const int m0 = bm * 256 + wm * 128 + fq * 4;
    const int n0 = bn * 256 + wn * 64 + fr;
#pragma unroll
    for (int i = 0; i < 8; ++i)
#pragma unroll
        for (int j = 0; j < 4; ++j)
#pragma unroll
            for (int r = 0; r < 4; ++r)
                Z[(size_t)(m0 + i * 16 + r) * HDIM + n0 + j * 16] = acc[i][j][r];
#undef STAGE_A
#undef STAGE_B
}

// ---------- Layer-1 approx IF recurrence + near-threshold flagging ----------
__global__ __launch_bounds__(256) void k_layer1_flag(const float* __restrict__ Z,
                                                     float* __restrict__ v1s,
                                                     uint64_t* __restrict__ S1,
                                                     uint64_t* __restrict__ flags,
                                                     int tbase, int first) {
    const size_t i = (size_t)blockIdx.x * 256 + threadIdx.x;
    float v = first ? 0.0f : v1s[i];
    const int lane = threadIdx.x & 63;
    const size_t word = i >> 6;
    uint64_t nearAcc = 0;
    for (int t = 0; t < TC; ++t) {
        v += Z[(size_t)t * BH + i];
        bool s    = (v >= 1.0f);
        bool near = (fabsf(v - 1.0f) < DELTA);
        unsigned long long sm = __ballot(s);
        nearAcc |= (uint64_t)__ballot(near);
        if (lane == 0) S1[(size_t)(tbase + t) * WORDS_PER_T + word] = sm;
        if (s) v = 0.0f;
    }
    if (lane == 0) flags[word] = first ? nearAcc : (flags[word] | nearAcc);
    v1s[i] = v;
}

// ---------- Exact fixup (r11/r13 version): recompute flagged (b,h) chains bitwise ----------
__global__ __launch_bounds__(256) void k_fixup(const float* __restrict__ x,
                                               const float* __restrict__ W1,
                                               const uint64_t* __restrict__ flags,
                                               uint64_t* __restrict__ S1) {
    __shared__ float xs[16][788];   // [t][k], rows 16B-aligned; 50.4 KB
    __shared__ int   list[FIXLIST];
    __shared__ int   cnt;
    const int b   = blockIdx.x;
    const int tid = threadIdx.x;
    if (tid == 0) cnt = 0;
    __syncthreads();
    if (tid < 64) {
        uint64_t w = flags[b * 64 + tid];
        while (w) {
            int bit = __builtin_ctzll(w);
            w &= w - 1;
            int p = atomicAdd(&cnt, 1);
            if (p < FIXLIST) list[p] = tid * 64 + bit;
        }
    }
    __syncthreads();
    const int n = min(cnt, FIXLIST);
    if (n == 0) return;

    for (int j0 = 0; j0 < n; j0 += 256) {
        const int j = j0 + tid;
        const int h = (j < n) ? list[j] : -1;
        const float* wrow = W1 + (size_t)(h >= 0 ? h : 0) * INDIM;
        float v = 0.0f;
        for (int half = 0; half < 2; ++half) {
            __syncthreads();   // previous pass done reading xs
            for (int idx = tid; idx < 16 * 196; idx += 256) {
                int t  = idx / 196;
                int kq = (idx % 196) * 4;
                *(float4*)&xs[t][kq] =
                    *(const float4*)(x + ((size_t)(half * 16 + t) * BATCH + b) * INDIM + kq);
            }
            __syncthreads();
            if (h >= 0) {
                float z[16];
#pragma unroll
                for (int t = 0; t < 16; ++t) z[t] = 0.0f;
                for (int kq = 0; kq < INDIM; kq += 4) {
                    float4 w4 = *(const float4*)(wrow + kq);
#pragma unroll
                    for (int t = 0; t < 16; ++t) {
                        float4 xv = *(const float4*)&xs[t][kq];   // wave-broadcast reads
                        z[t] = fmaf(xv.x, w4.x, z[t]);
                        z[t] = fmaf(xv.y, w4.y, z[t]);
                        z[t] = fmaf(xv.z, w4.z, z[t]);
                        z[t] = fmaf(xv.w, w4.w, z[t]);
                    }
                }
#pragma unroll
                for (int t = 0; t < 16; ++t) {
                    v += z[t];
                    bool s = (v >= 1.0f);
                    unsigned long long* wp = (unsigned long long*)
                        &S1[(size_t)(half * 16 + t) * WORDS_PER_T + (size_t)b * 64 + (h >> 6)];
                    unsigned long long m = 1ull << (h & 63);
                    if (s) { atomicOr(wp, m); v = 0.0f; }
                    else   { atomicAnd(wp, ~m); }
                }
            }
        }
    }
}

// ---------- Layer-2 partial sums from spike bitmask ----------
__global__ __launch_bounds__(256) void k_layer2_partial(const uint64_t* __restrict__ S1,
                                                        const float* __restrict__ W2T,
                                                        float* __restrict__ part,
                                                        int rowsTotal) {
    __shared__ float w[1024][10];   // 40 KB
    const int hs = blockIdx.y;
    for (int i = threadIdx.x; i < 1024 * 10; i += 256)
        w[i / 10][i % 10] = W2T[hs * 1024 * 10 + i];
    __syncthreads();

    const int row = blockIdx.x * 256 + threadIdx.x;
    const uint64_t* wp = S1 + (size_t)row * 64 + hs * 16;
    float acc[10] = {};
    for (int wi = 0; wi < 16; ++wi) {
        uint64_t m = wp[wi];
        while (m) {
            int bit = __builtin_ctzll(m);
            m &= m - 1;
            int hl = wi * 64 + bit;
#pragma unroll
            for (int o = 0; o < 10; ++o) acc[o] += w[hl][o];
        }
    }
    float* p = part + ((size_t)hs * rowsTotal + row) * 10;
#pragma unroll
    for (int o = 0; o < 10; ++o) p[o] = acc[o];
}

// ---------- Layer-2 IF recurrence + spike record ----------
__global__ __launch_bounds__(256) void k_layer2_rec(const float* __restrict__ part,
                                                    float* __restrict__ out) {
    const int i = blockIdx.x * 256 + threadIdx.x;
    if (i >= BATCH * OUTDIM) return;
    float v = 0.0f, rec = 0.0f;
    const int rowsTotal = T_TOTAL * BATCH;
    const int b = i / OUTDIM, o = i % OUTDIM;
    for (int t = 0; t < T_TOTAL; ++t) {
        const int r = t * BATCH + b;
        float sig = 0.0f;
#pragma unroll
        for (int hs = 0; hs < 4; ++hs)
            sig += part[((size_t)hs * rowsTotal + r) * 10 + o];
        v += sig;
        bool s = (v >= 1.0f);
        rec += s ? 1.0f : 0.0f;
        if (s) v = 0.0f;
    }
    out[i] = rec;
}

// ---------- launch ----------
extern "C" void kernel_launch(void* const* d_in, const int* in_sizes, int n_in,
                              void* d_out, int out_size, void* d_ws, size_t ws_size,
                              hipStream_t stream) {
    (void)in_sizes; (void)n_in; (void)out_size; (void)ws_size;
    const float* x  = (const float*)d_in[0];   // [32][1024][784]
    const float* W1 = (const float*)d_in[1];   // [4096][784]
    const float* W2 = (const float*)d_in[2];   // [10][4096]
    float* out = (float*)d_out;                // [1024][10]

    // ws layout (total ~230 MB)
    char* p = (char*)d_ws;
    float*    W2T   = (float*)p;    p += (size_t)HDIM * OUTDIM * 4;        // 160 KB
    float*    v1s   = (float*)p;    p += (size_t)BH * 4;                   // 16.8 MB
    ushort*   Bp    = (ushort*)p;   p += (size_t)HDIM * KP * 2;            // 19.4 MB
    ushort*   Ap    = (ushort*)p;   p += (size_t)MC * KP * 2;              // 38.8 MB
    float*    Z     = (float*)p;    p += (size_t)TC * BH * 4;              // 134.2 MB
    uint64_t* S1    = (uint64_t*)p; p += (size_t)T_TOTAL * WORDS_PER_T * 8;// 16.8 MB
    uint64_t* flags = (uint64_t*)p; p += (size_t)WORDS_PER_T * 8;          // 0.5 MB
    float*    part  = (float*)p;                                           // 5.2 MB

    k_transpose_w2<<<(HDIM * OUTDIM + 255) / 256, 256, 0, stream>>>(W2, W2T);
    k_split3<<<(HDIM * 400 + 255) / 256, 256, 0, stream>>>(W1, Bp, HDIM, 0);

    const int nch = T_TOTAL / TC;   // 4
    for (int c = 0; c < nch; ++c) {
        const float* xc = x + (size_t)c * MC * INDIM;
        k_split3<<<(MC * 400 + 255) / 256, 256, 0, stream>>>(xc, Ap, MC, 1);
        k_gemm_bf16<<<(MC / 256) * (HDIM / 256), 512, 0, stream>>>(Ap, Bp, Z);
        k_layer1_flag<<<BH / 256, 256, 0, stream>>>(Z, v1s, S1, flags, c * TC, c == 0);
    }
    k_fixup<<<BATCH, 256, 0, stream>>>(x, W1, flags, S1);
    k_layer2_partial<<<dim3(T_TOTAL * BATCH / 256, 4), 256, 0, stream>>>(
        S1, W2T, part, T_TOTAL * BATCH);
    k_layer2_rec<<<(BATCH * OUTDIM + 255) / 256, 256, 0, stream>>>(part, out);
}

// Round 15
// 1234.694 us; speedup vs baseline: 1.3991x; 1.0023x over previous
//
#include <hip/hip_runtime.h>
#include <stdint.h>

typedef __attribute__((ext_vector_type(8))) short bf16x8;
typedef __attribute__((ext_vector_type(4))) float f32x4;

#define T_TOTAL 32
#define BATCH   1024
#define INDIM   784
#define HDIM    4096
#define OUTDIM  10
#define BH      (BATCH * HDIM)      // 4,194,304
#define WORDS_PER_T (BH / 64)       // 65,536 u64 words per timestep
#define TC      8                   // timesteps per GEMM chunk
#define MC      (TC * BATCH)        // 8192 rows per chunk
// concat-K layout (small-magnitude segments first, hh LAST):
// [0,784)=hm [784,1568)=mh [1568,2352)=hh [2352,2368)=0
#define KP      2368                // 74 * 32
#define NT      74                  // K-tiles of 32
// Near-threshold flag window. Error model: dropped terms (mm + l-residuals,
// 2352 bounded iid random-sign terms) give z-err rms ~1.2e-5, run-accumulated
// <~4e-5; Hoeffding P(|v_err|>5e-4) has exponent >>10 -> 0 expected misses
// over 1.3e8 decisions. r9-r13 passed at 2e-3; 5e-4 quarters the flag count
// -> 1 active fixup wave/block instead of 4 (fixup is LDS-pipe-bound, r11/r12).
#define DELTA   5e-4f
#define FIXLIST 3072

// ---------- 2-way bf16 truncation split: a = h + m + residual(~2^-16) ----------
__device__ __forceinline__ void split2(float a, ushort& h, ushort& m) {
    unsigned ua = __float_as_uint(a);
    h = (ushort)(ua >> 16);
    float r = a - __uint_as_float(ua & 0xFFFF0000u);   // exact
    m = (ushort)(__float_as_uint(r) >> 16);
}

// ---------- split fp32 [R][784] into concat-K bf16 [R][2368] ----------
__global__ __launch_bounds__(256) void k_split3(const float* __restrict__ src,
                                                ushort* __restrict__ dst,
                                                int R, int isA) {
    int idx = blockIdx.x * 256 + threadIdx.x;
    int main_n = R * 392;                       // 784/2 pairs per row
    if (idx < main_n) {
        int row = idx / 392, kk = (idx % 392) * 2;
        float a0 = src[(size_t)row * INDIM + kk];
        float a1 = src[(size_t)row * INDIM + kk + 1];
        ushort h0, m0, h1, m1;
        split2(a0, h0, m0);
        split2(a1, h1, m1);
        ushort2 H; H.x = h0; H.y = h1;
        ushort2 M; M.x = m0; M.y = m1;
        ushort2 s1 = isA ? H : M;   // hm: A=h, B=m
        ushort2 s2 = isA ? M : H;   // mh: A=m, B=h
        ushort* d = dst + (size_t)row * KP;
        *(ushort2*)(d + kk)        = s1;  // hm
        *(ushort2*)(d + 784 + kk)  = s2;  // mh
        *(ushort2*)(d + 1568 + kk) = H;   // hh (accumulated last)
    } else if (idx < main_n + R * 8) {
        int j = idx - main_n;
        int row = j / 8, q = j % 8;
        ushort2 z; z.x = 0; z.y = 0;
        *(ushort2*)(dst + (size_t)row * KP + 2352 + q * 2) = z;
    }
}

// ---------- W2 transpose: W2[10][4096] -> W2T[4096][10] ----------
__global__ void k_transpose_w2(const float* __restrict__ W2, float* __restrict__ W2T) {
    int i = blockIdx.x * 256 + threadIdx.x;
    if (i < HDIM * OUTDIM) {
        int h = i / OUTDIM, o = i % OUTDIM;
        W2T[i] = W2[o * HDIM + h];
    }
}

// ---------- bf16 MFMA GEMM, pipelined (T3+T4+T5): 256x256 tile, BK=32 ----------
// (r13-verified: 1313us total, absmax 0.0, ~840 TF) 512 thr = 8 waves (2m x 4n).
// Double-buffered LDS (slot = t&1, 64 KB), raw s_barrier + counted vmcnt(2):
//   tile t: [vmcnt(2); barrier] P0{read FA[0..7],FB[0..1]; issue B(t+1)->s^1; 16 MFMA}
//           [barrier] P1{issue A(t+2)->s; read FB[2..3]; 16 MFMA}
__global__ __launch_bounds__(512) void k_gemm_bf16(const ushort* __restrict__ Ap,
                                                   const ushort* __restrict__ Bp,
                                                   float* __restrict__ Z) {
    __shared__ ushort Asm[2][256 * 32];   // 2 x 16 KB
    __shared__ ushort Bsm[2][256 * 32];   // 2 x 16 KB

    // XCD-bijective swizzle (gridDim.x = 512, % 8 == 0)
    const int cpx = gridDim.x >> 3;
    const int swz = (blockIdx.x & 7) * cpx + (blockIdx.x >> 3);
    const int bm  = swz >> 4;            // 32 m-blocks (MC/256)
    const int bn  = swz & 15;            // 16 n-blocks (HDIM/256)

    const int tid  = threadIdx.x;
    const int wid  = tid >> 6, lane = tid & 63;
    const int wm   = wid >> 2, wn = wid & 3;
    const int fr   = lane & 15, fq = lane >> 4;

    const int srow  = tid >> 2;           // 0..127
    const int skcol = (tid & 3) << 3;     // 0,8,16,24
    const ushort* agb = Ap + (size_t)(bm * 256 + srow) * KP + skcol;
    const ushort* bgb = Bp + (size_t)(bn * 256 + srow) * KP + skcol;
    const int sbase = wid * 16 * 32;      // wave-uniform LDS base (elements)

#define STAGE_A(t, s) do {                                                            \
    __builtin_amdgcn_global_load_lds(                                                 \
        (const __attribute__((address_space(1))) void*)(agb + (size_t)(t) * 32),      \
        (__attribute__((address_space(3))) void*)(&Asm[s][sbase]), 16, 0, 0);         \
    __builtin_amdgcn_global_load_lds(                                                 \
        (const __attribute__((address_space(1))) void*)(agb + (size_t)(t) * 32 + (size_t)128 * KP), \
        (__attribute__((address_space(3))) void*)(&Asm[s][4096 + sbase]), 16, 0, 0);  \
} while (0)
#define STAGE_B(t, s) do {                                                            \
    __builtin_amdgcn_global_load_lds(                                                 \
        (const __attribute__((address_space(1))) void*)(bgb + (size_t)(t) * 32),      \
        (__attribute__((address_space(3))) void*)(&Bsm[s][sbase]), 16, 0, 0);         \
    __builtin_amdgcn_global_load_lds(                                                 \
        (const __attribute__((address_space(1))) void*)(bgb + (size_t)(t) * 32 + (size_t)128 * KP), \
        (__attribute__((address_space(3))) void*)(&Bsm[s][4096 + sbase]), 16, 0, 0);  \
} while (0)

    f32x4 acc[8][4];
#pragma unroll
    for (int i = 0; i < 8; ++i)
#pragma unroll
        for (int j = 0; j < 4; ++j) acc[i][j] = (f32x4){0.f, 0.f, 0.f, 0.f};

    const int aidx = (wm * 128 + fr) * 4 + fq;   // + i*64
    const int bidx = (wn * 64 + fr) * 4 + fq;    // + j*64

    // prologue: A(0),B(0) -> slot0; A(1) -> slot1  (6 issues outstanding)
    STAGE_A(0, 0);
    STAGE_B(0, 0);
    STAGE_A(1, 1);

    for (int t = 0; t < NT; ++t) {
        const int s = t & 1;
        if (t == NT - 1) asm volatile("s_waitcnt vmcnt(0)" ::: "memory");
        else             asm volatile("s_waitcnt vmcnt(2)" ::: "memory");
        __builtin_amdgcn_s_barrier();

        const bf16x8* A8 = (const bf16x8*)Asm[s];
        const bf16x8* B8 = (const bf16x8*)Bsm[s];

        // ---- P0 ----
        bf16x8 fa[8];
#pragma unroll
        for (int i = 0; i < 8; ++i) fa[i] = A8[aidx + i * 64];
        bf16x8 fb0 = B8[bidx];
        bf16x8 fb1 = B8[bidx + 64];
        if (t + 1 < NT) STAGE_B(t + 1, s ^ 1);
        __builtin_amdgcn_s_setprio(1);
#pragma unroll
        for (int i = 0; i < 8; ++i) {
            acc[i][0] = __builtin_amdgcn_mfma_f32_16x16x32_bf16(fa[i], fb0, acc[i][0], 0, 0, 0);
            acc[i][1] = __builtin_amdgcn_mfma_f32_16x16x32_bf16(fa[i], fb1, acc[i][1], 0, 0, 0);
        }
        __builtin_amdgcn_s_setprio(0);

        // ---- P1 ----
        __builtin_amdgcn_s_barrier();         // all P0 A-reads issued before A-overwrite
        if (t + 2 < NT) STAGE_A(t + 2, s);
        bf16x8 fb2 = B8[bidx + 128];
        bf16x8 fb3 = B8[bidx + 192];
        __builtin_amdgcn_s_setprio(1);
#pragma unroll
        for (int i = 0; i < 8; ++i) {
            acc[i][2] = __builtin_amdgcn_mfma_f32_16x16x32_bf16(fa[i], fb2, acc[i][2], 0, 0, 0);
            acc[i][3] = __builtin_amdgcn_mfma_f32_16x16x32_bf16(fa[i], fb3, acc[i][3], 0, 0, 0);
        }
        __builtin_amdgcn_s_setprio(0);
    }

    // C/D layout (m89-verified): col = lane&15, row = (lane>>4)*4 + reg
    const int m0 = bm * 256 + wm * 128 + fq * 4;
    const int n0 = bn * 256 + wn * 64 + fr;
#pragma unroll
    for (int i = 0; i < 8; ++i)
#pragma unroll
        for (int j = 0; j < 4; ++j)
#pragma unroll
            for (int r = 0; r < 4; ++r)
                Z[(size_t)(m0 + i * 16 + r) * HDIM + n0 + j * 16] = acc[i][j][r];
#undef STAGE_A
#undef STAGE_B
}

// ---------- Layer-1 approx IF recurrence + near-threshold flagging ----------
__global__ __launch_bounds__(256) void k_layer1_flag(const float* __restrict__ Z,
                                                     float* __restrict__ v1s,
                                                     uint64_t* __restrict__ S1,
                                                     uint64_t* __restrict__ flags,
                                                     int tbase, int first) {
    const size_t i = (size_t)blockIdx.x * 256 + threadIdx.x;
    float v = first ? 0.0f : v1s[i];
    const int lane = threadIdx.x & 63;
    const size_t word = i >> 6;
    uint64_t nearAcc = 0;
    for (int t = 0; t < TC; ++t) {
        v += Z[(size_t)t * BH + i];
        bool s    = (v >= 1.0f);
        bool near = (fabsf(v - 1.0f) < DELTA);
        unsigned long long sm = __ballot(s);
        nearAcc |= (uint64_t)__ballot(near);
        if (lane == 0) S1[(size_t)(tbase + t) * WORDS_PER_T + word] = sm;
        if (s) v = 0.0f;
    }
    if (lane == 0) flags[word] = first ? nearAcc : (flags[word] | nearAcc);
    v1s[i] = v;
}

// ---------- Exact fixup (r11/r13 version): recompute flagged (b,h) chains bitwise ----------
__global__ __launch_bounds__(256) void k_fixup(const float* __restrict__ x,
                                               const float* __restrict__ W1,
                                               const uint64_t* __restrict__ flags,
                                               uint64_t* __restrict__ S1) {
    __shared__ float xs[16][788];   // [t][k], rows 16B-aligned; 50.4 KB
    __shared__ int   list[FIXLIST];
    __shared__ int   cnt;
    const int b   = blockIdx.x;
    const int tid = threadIdx.x;
    if (tid == 0) cnt = 0;
    __syncthreads();
    if (tid < 64) {
        uint64_t w = flags[b * 64 + tid];
        while (w) {
            int bit = __builtin_ctzll(w);
            w &= w - 1;
            int p = atomicAdd(&cnt, 1);
            if (p < FIXLIST) list[p] = tid * 64 + bit;
        }
    }
    __syncthreads();
    const int n = min(cnt, FIXLIST);
    if (n == 0) return;

    for (int j0 = 0; j0 < n; j0 += 256) {
        const int j = j0 + tid;
        const int h = (j < n) ? list[j] : -1;
        const float* wrow = W1 + (size_t)(h >= 0 ? h : 0) * INDIM;
        float v = 0.0f;
        for (int half = 0; half < 2; ++half) {
            __syncthreads();   // previous pass done reading xs
            for (int idx = tid; idx < 16 * 196; idx += 256) {
                int t  = idx / 196;
                int kq = (idx % 196) * 4;
                *(float4*)&xs[t][kq] =
                    *(const float4*)(x + ((size_t)(half * 16 + t) * BATCH + b) * INDIM + kq);
            }
            __syncthreads();
            if (h >= 0) {
                float z[16];
#pragma unroll
                for (int t = 0; t < 16; ++t) z[t] = 0.0f;
                for (int kq = 0; kq < INDIM; kq += 4) {
                    float4 w4 = *(const float4*)(wrow + kq);
#pragma unroll
                    for (int t = 0; t < 16; ++t) {
                        float4 xv = *(const float4*)&xs[t][kq];   // wave-broadcast reads
                        z[t] = fmaf(xv.x, w4.x, z[t]);
                        z[t] = fmaf(xv.y, w4.y, z[t]);
                        z[t] = fmaf(xv.z, w4.z, z[t]);
                        z[t] = fmaf(xv.w, w4.w, z[t]);
                    }
                }
#pragma unroll
                for (int t = 0; t < 16; ++t) {
                    v += z[t];
                    bool s = (v >= 1.0f);
                    unsigned long long* wp = (unsigned long long*)
                        &S1[(size_t)(half * 16 + t) * WORDS_PER_T + (size_t)b * 64 + (h >> 6)];
                    unsigned long long m = 1ull << (h & 63);
                    if (s) { atomicOr(wp, m); v = 0.0f; }
                    else   { atomicAnd(wp, ~m); }
                }
            }
        }
    }
}

// ---------- Layer-2 partial sums from spike bitmask ----------
__global__ __launch_bounds__(256) void k_layer2_partial(const uint64_t* __restrict__ S1,
                                                        const float* __restrict__ W2T,
                                                        float* __restrict__ part,
                                                        int rowsTotal) {
    __shared__ float w[1024][10];   // 40 KB
    const int hs = blockIdx.y;
    for (int i = threadIdx.x; i < 1024 * 10; i += 256)
        w[i / 10][i % 10] = W2T[hs * 1024 * 10 + i];
    __syncthreads();

    const int row = blockIdx.x * 256 + threadIdx.x;
    const uint64_t* wp = S1 + (size_t)row * 64 + hs * 16;
    float acc[10] = {};
    for (int wi = 0; wi < 16; ++wi) {
        uint64_t m = wp[wi];
        while (m) {
            int bit = __builtin_ctzll(m);
            m &= m - 1;
            int hl = wi * 64 + bit;
#pragma unroll
            for (int o = 0; o < 10; ++o) acc[o] += w[hl][o];
        }
    }
    float* p = part + ((size_t)hs * rowsTotal + row) * 10;
#pragma unroll
    for (int o = 0; o < 10; ++o) p[o] = acc[o];
}

// ---------- Layer-2 IF recurrence + spike record ----------
__global__ __launch_bounds__(256) void k_layer2_rec(const float* __restrict__ part,
                                                    float* __restrict__ out) {
    const int i = blockIdx.x * 256 + threadIdx.x;
    if (i >= BATCH * OUTDIM) return;
    float v = 0.0f, rec = 0.0f;
    const int rowsTotal = T_TOTAL * BATCH;
    const int b = i / OUTDIM, o = i % OUTDIM;
    for (int t = 0; t < T_TOTAL; ++t) {
        const int r = t * BATCH + b;
        float sig = 0.0f;
#pragma unroll
        for (int hs = 0; hs < 4; ++hs)
            sig += part[((size_t)hs * rowsTotal + r) * 10 + o];
        v += sig;
        bool s = (v >= 1.0f);
        rec += s ? 1.0f : 0.0f;
        if (s) v = 0.0f;
    }
    out[i] = rec;
}

// ---------- launch ----------
extern "C" void kernel_launch(void* const* d_in, const int* in_sizes, int n_in,
                              void* d_out, int out_size, void* d_ws, size_t ws_size,
                              hipStream_t stream) {
    (void)in_sizes; (void)n_in; (void)out_size; (void)ws_size;
    const float* x  = (const float*)d_in[0];   // [32][1024][784]
    const float* W1 = (const float*)d_in[1];   // [4096][784]
    const float* W2 = (const float*)d_in[2];   // [10][4096]
    float* out = (float*)d_out;                // [1024][10]

    // ws layout (total ~230 MB)
    char* p = (char*)d_ws;
    float*    W2T   = (float*)p;    p += (size_t)HDIM * OUTDIM * 4;        // 160 KB
    float*    v1s   = (float*)p;    p += (size_t)BH * 4;                   // 16.8 MB
    ushort*   Bp    = (ushort*)p;   p += (size_t)HDIM * KP * 2;            // 19.4 MB
    ushort*   Ap    = (ushort*)p;   p += (size_t)MC * KP * 2;              // 38.8 MB
    float*    Z     = (float*)p;    p += (size_t)TC * BH * 4;              // 134.2 MB
    uint64_t* S1    = (uint64_t*)p; p += (size_t)T_TOTAL * WORDS_PER_T * 8;// 16.8 MB
    uint64_t* flags = (uint64_t*)p; p += (size_t)WORDS_PER_T * 8;          // 0.5 MB
    float*    part  = (float*)p;                                           // 5.2 MB

    k_transpose_w2<<<(HDIM * OUTDIM + 255) / 256, 256, 0, stream>>>(W2, W2T);
    k_split3<<<(HDIM * 400 + 255) / 256, 256, 0, stream>>>(W1, Bp, HDIM, 0);

    const int nch = T_TOTAL / TC;   // 4
    for (int c = 0; c < nch; ++c) {
        const float* xc = x + (size_t)c * MC * INDIM;
        k_split3<<<(MC * 400 + 255) / 256, 256, 0, stream>>>(xc, Ap, MC, 1);
        k_gemm_bf16<<<(MC / 256) * (HDIM / 256), 512, 0, stream>>>(Ap, Bp, Z);
        k_layer1_flag<<<BH / 256, 256, 0, stream>>>(Z, v1s, S1, flags, c * TC, c == 0);
    }
    k_fixup<<<BATCH, 256, 0, stream>>>(x, W1, flags, S1);
    k_layer2_partial<<<dim3(T_TOTAL * BATCH / 256, 4), 256, 0, stream>>>(
        S1, W2T, part, T_TOTAL * BATCH);
    k_layer2_rec<<<(BATCH * OUTDIM + 255) / 256, 256, 0, stream>>>(part, out);
}

// Round 16
// 1228.780 us; speedup vs baseline: 1.4059x; 1.0048x over previous
//
#include <hip/hip_runtime.h>
#include <stdint.h>

typedef __attribute__((ext_vector_type(8))) short bf16x8;
typedef __attribute__((ext_vector_type(4))) float f32x4;

#define T_TOTAL 32
#define BATCH   1024
#define INDIM   784
#define HDIM    4096
#define OUTDIM  10
#define BH      (BATCH * HDIM)      // 4,194,304
#define WORDS_PER_T (BH / 64)       // 65,536 u64 words per timestep
#define TC      8                   // timesteps per GEMM chunk
#define MC      (TC * BATCH)        // 8192 rows per chunk
// concat-K layout (small-magnitude segments first, hh LAST):
// [0,784)=hm [784,1568)=mh [1568,2352)=hh [2352,2368)=0
#define KP      2368                // 74 * 32
#define NT      74                  // K-tiles of 32
// Near-threshold flag window. Error model: dropped terms (mm + l-residuals,
// 2352 bounded iid random-sign terms) give z-err rms ~1.2e-5, run-accumulated
// <~4e-5; Hoeffding P(|v_err|>5e-4) has exponent >>10 -> 0 expected misses
// over 1.3e8 decisions. r9-r13 passed at 2e-3; 5e-4 quarters the flag count
// -> 1 active fixup wave/block instead of 4 (fixup is LDS-pipe-bound, r11/r12).
#define DELTA   5e-4f
#define FIXLIST 3072

// ---------- 2-way bf16 truncation split: a = h + m + residual(~2^-16) ----------
__device__ __forceinline__ void split2(float a, ushort& h, ushort& m) {
    unsigned ua = __float_as_uint(a);
    h = (ushort)(ua >> 16);
    float r = a - __uint_as_float(ua & 0xFFFF0000u);   // exact
    m = (ushort)(__float_as_uint(r) >> 16);
}

// ---------- split fp32 [R][784] into concat-K bf16 [R][2368] ----------
__global__ __launch_bounds__(256) void k_split3(const float* __restrict__ src,
                                                ushort* __restrict__ dst,
                                                int R, int isA) {
    int idx = blockIdx.x * 256 + threadIdx.x;
    int main_n = R * 392;                       // 784/2 pairs per row
    if (idx < main_n) {
        int row = idx / 392, kk = (idx % 392) * 2;
        float a0 = src[(size_t)row * INDIM + kk];
        float a1 = src[(size_t)row * INDIM + kk + 1];
        ushort h0, m0, h1, m1;
        split2(a0, h0, m0);
        split2(a1, h1, m1);
        ushort2 H; H.x = h0; H.y = h1;
        ushort2 M; M.x = m0; M.y = m1;
        ushort2 s1 = isA ? H : M;   // hm: A=h, B=m
        ushort2 s2 = isA ? M : H;   // mh: A=m, B=h
        ushort* d = dst + (size_t)row * KP;
        *(ushort2*)(d + kk)        = s1;  // hm
        *(ushort2*)(d + 784 + kk)  = s2;  // mh
        *(ushort2*)(d + 1568 + kk) = H;   // hh (accumulated last)
    } else if (idx < main_n + R * 8) {
        int j = idx - main_n;
        int row = j / 8, q = j % 8;
        ushort2 z; z.x = 0; z.y = 0;
        *(ushort2*)(dst + (size_t)row * KP + 2352 + q * 2) = z;
    }
}

// ---------- W2 transpose: W2[10][4096] -> W2T[4096][10] ----------
__global__ void k_transpose_w2(const float* __restrict__ W2, float* __restrict__ W2T) {
    int i = blockIdx.x * 256 + threadIdx.x;
    if (i < HDIM * OUTDIM) {
        int h = i / OUTDIM, o = i % OUTDIM;
        W2T[i] = W2[o * HDIM + h];
    }
}

// ---------- bf16 MFMA GEMM, pipelined (T3+T4+T5): 256x256 tile, BK=32 ----------
// (r13-verified: 1313us total, absmax 0.0, ~840 TF) 512 thr = 8 waves (2m x 4n).
// Double-buffered LDS (slot = t&1, 64 KB), raw s_barrier + counted vmcnt(2):
//   tile t: [vmcnt(2); barrier] P0{read FA[0..7],FB[0..1]; issue B(t+1)->s^1; 16 MFMA}
//           [barrier] P1{issue A(t+2)->s; read FB[2..3]; 16 MFMA}
__global__ __launch_bounds__(512) void k_gemm_bf16(const ushort* __restrict__ Ap,
                                                   const ushort* __restrict__ Bp,
                                                   float* __restrict__ Z) {
    __shared__ ushort Asm[2][256 * 32];   // 2 x 16 KB
    __shared__ ushort Bsm[2][256 * 32];   // 2 x 16 KB

    // XCD-bijective swizzle (gridDim.x = 512, % 8 == 0)
    const int cpx = gridDim.x >> 3;
    const int swz = (blockIdx.x & 7) * cpx + (blockIdx.x >> 3);
    const int bm  = swz >> 4;            // 32 m-blocks (MC/256)
    const int bn  = swz & 15;            // 16 n-blocks (HDIM/256)

    const int tid  = threadIdx.x;
    const int wid  = tid >> 6, lane = tid & 63;
    const int wm   = wid >> 2, wn = wid & 3;
    const int fr   = lane & 15, fq = lane >> 4;

    const int srow  = tid >> 2;           // 0..127
    const int skcol = (tid & 3) << 3;     // 0,8,16,24
    const ushort* agb = Ap + (size_t)(bm * 256 + srow) * KP + skcol;
    const ushort* bgb = Bp + (size_t)(bn * 256 + srow) * KP + skcol;
    const int sbase = wid * 16 * 32;      // wave-uniform LDS base (elements)

#define STAGE_A(t, s) do {                                                            \
    __builtin_amdgcn_global_load_lds(                                                 \
        (const __attribute__((address_space(1))) void*)(agb + (size_t)(t) * 32),      \
        (__attribute__((address_space(3))) void*)(&Asm[s][sbase]), 16, 0, 0);         \
    __builtin_amdgcn_global_load_lds(                                                 \
        (const __attribute__((address_space(1))) void*)(agb + (size_t)(t) * 32 + (size_t)128 * KP), \
        (__attribute__((address_space(3))) void*)(&Asm[s][4096 + sbase]), 16, 0, 0);  \
} while (0)
#define STAGE_B(t, s) do {                                                            \
    __builtin_amdgcn_global_load_lds(                                                 \
        (const __attribute__((address_space(1))) void*)(bgb + (size_t)(t) * 32),      \
        (__attribute__((address_space(3))) void*)(&Bsm[s][sbase]), 16, 0, 0);         \
    __builtin_amdgcn_global_load_lds(                                                 \
        (const __attribute__((address_space(1))) void*)(bgb + (size_t)(t) * 32 + (size_t)128 * KP), \
        (__attribute__((address_space(3))) void*)(&Bsm[s][4096 + sbase]), 16, 0, 0);  \
} while (0)

    f32x4 acc[8][4];
#pragma unroll
    for (int i = 0; i < 8; ++i)
#pragma unroll
        for (int j = 0; j < 4; ++j) acc[i][j] = (f32x4){0.f, 0.f, 0.f, 0.f};

    const int aidx = (wm * 128 + fr) * 4 + fq;   // + i*64
    const int bidx = (wn * 64 + fr) * 4 + fq;    // + j*64

    // prologue: A(0),B(0) -> slot0; A(1) -> slot1  (6 issues outstanding)
    STAGE_A(0, 0);
    STAGE_B(0, 0);
    STAGE_A(1, 1);

    for (int t = 0; t < NT; ++t) {
        const int s = t & 1;
        if (t == NT - 1) asm volatile("s_waitcnt vmcnt(0)" ::: "memory");
        else             asm volatile("s_waitcnt vmcnt(2)" ::: "memory");
        __builtin_amdgcn_s_barrier();

        const bf16x8* A8 = (const bf16x8*)Asm[s];
        const bf16x8* B8 = (const bf16x8*)Bsm[s];

        // ---- P0 ----
        bf16x8 fa[8];
#pragma unroll
        for (int i = 0; i < 8; ++i) fa[i] = A8[aidx + i * 64];
        bf16x8 fb0 = B8[bidx];
        bf16x8 fb1 = B8[bidx + 64];
        if (t + 1 < NT) STAGE_B(t + 1, s ^ 1);
        __builtin_amdgcn_s_setprio(1);
#pragma unroll
        for (int i = 0; i < 8; ++i) {
            acc[i][0] = __builtin_amdgcn_mfma_f32_16x16x32_bf16(fa[i], fb0, acc[i][0], 0, 0, 0);
            acc[i][1] = __builtin_amdgcn_mfma_f32_16x16x32_bf16(fa[i], fb1, acc[i][1], 0, 0, 0);
        }
        __builtin_amdgcn_s_setprio(0);

        // ---- P1 ----
        __builtin_amdgcn_s_barrier();         // all P0 A-reads issued before A-overwrite
        if (t + 2 < NT) STAGE_A(t + 2, s);
        bf16x8 fb2 = B8[bidx + 128];
        bf16x8 fb3 = B8[bidx + 192];
        __builtin_amdgcn_s_setprio(1);
#pragma unroll
        for (int i = 0; i < 8; ++i) {
            acc[i][2] = __builtin_amdgcn_mfma_f32_16x16x32_bf16(fa[i], fb2, acc[i][2], 0, 0, 0);
            acc[i][3] = __builtin_amdgcn_mfma_f32_16x16x32_bf16(fa[i], fb3, acc[i][3], 0, 0, 0);
        }
        __builtin_amdgcn_s_setprio(0);
    }

    // C/D layout (m89-verified): col = lane&15, row = (lane>>4)*4 + reg
    const int m0 = bm * 256 + wm * 128 + fq * 4;
    const int n0 = bn * 256 + wn * 64 + fr;
#pragma unroll
    for (int i = 0; i < 8; ++i)
#pragma unroll
        for (int j = 0; j < 4; ++j)
#pragma unroll
            for (int r = 0; r < 4; ++r)
                Z[(size_t)(m0 + i * 16 + r) * HDIM + n0 + j * 16] = acc[i][j][r];
#undef STAGE_A
#undef STAGE_B
}

// ---------- Layer-1 approx IF recurrence + near-threshold flagging ----------
__global__ __launch_bounds__(256) void k_layer1_flag(const float* __restrict__ Z,
                                                     float* __restrict__ v1s,
                                                     uint64_t* __restrict__ S1,
                                                     uint64_t* __restrict__ flags,
                                                     int tbase, int first) {
    const size_t i = (size_t)blockIdx.x * 256 + threadIdx.x;
    float v = first ? 0.0f : v1s[i];
    const int lane = threadIdx.x & 63;
    const size_t word = i >> 6;
    uint64_t nearAcc = 0;
    for (int t = 0; t < TC; ++t) {
        v += Z[(size_t)t * BH + i];
        bool s    = (v >= 1.0f);
        bool near = (fabsf(v - 1.0f) < DELTA);
        unsigned long long sm = __ballot(s);
        nearAcc |= (uint64_t)__ballot(near);
        if (lane == 0) S1[(size_t)(tbase + t) * WORDS_PER_T + word] = sm;
        if (s) v = 0.0f;
    }
    if (lane == 0) flags[word] = first ? nearAcc : (flags[word] | nearAcc);
    v1s[i] = v;
}

// ---------- Exact fixup (r11/r13 version): recompute flagged (b,h) chains bitwise ----------
__global__ __launch_bounds__(256) void k_fixup(const float* __restrict__ x,
                                               const float* __restrict__ W1,
                                               const uint64_t* __restrict__ flags,
                                               uint64_t* __restrict__ S1) {
    __shared__ float xs[16][788];   // [t][k], rows 16B-aligned; 50.4 KB
    __shared__ int   list[FIXLIST];
    __shared__ int   cnt;
    const int b   = blockIdx.x;
    const int tid = threadIdx.x;
    if (tid == 0) cnt = 0;
    __syncthreads();
    if (tid < 64) {
        uint64_t w = flags[b * 64 + tid];
        while (w) {
            int bit = __builtin_ctzll(w);
            w &= w - 1;
            int p = atomicAdd(&cnt, 1);
            if (p < FIXLIST) list[p] = tid * 64 + bit;
        }
    }
    __syncthreads();
    const int n = min(cnt, FIXLIST);
    if (n == 0) return;

    for (int j0 = 0; j0 < n; j0 += 256) {
        const int j = j0 + tid;
        const int h = (j < n) ? list[j] : -1;
        const float* wrow = W1 + (size_t)(h >= 0 ? h : 0) * INDIM;
        float v = 0.0f;
        for (int half = 0; half < 2; ++half) {
            __syncthreads();   // previous pass done reading xs
            for (int idx = tid; idx < 16 * 196; idx += 256) {
                int t  = idx / 196;
                int kq = (idx % 196) * 4;
                *(float4*)&xs[t][kq] =
                    *(const float4*)(x + ((size_t)(half * 16 + t) * BATCH + b) * INDIM + kq);
            }
            __syncthreads();
            if (h >= 0) {
                float z[16];
#pragma unroll
                for (int t = 0; t < 16; ++t) z[t] = 0.0f;
                for (int kq = 0; kq < INDIM; kq += 4) {
                    float4 w4 = *(const float4*)(wrow + kq);
#pragma unroll
                    for (int t = 0; t < 16; ++t) {
                        float4 xv = *(const float4*)&xs[t][kq];   // wave-broadcast reads
                        z[t] = fmaf(xv.x, w4.x, z[t]);
                        z[t] = fmaf(xv.y, w4.y, z[t]);
                        z[t] = fmaf(xv.z, w4.z, z[t]);
                        z[t] = fmaf(xv.w, w4.w, z[t]);
                    }
                }
#pragma unroll
                for (int t = 0; t < 16; ++t) {
                    v += z[t];
                    bool s = (v >= 1.0f);
                    unsigned long long* wp = (unsigned long long*)
                        &S1[(size_t)(half * 16 + t) * WORDS_PER_T + (size_t)b * 64 + (h >> 6)];
                    unsigned long long m = 1ull << (h & 63);
                    if (s) { atomicOr(wp, m); v = 0.0f; }
                    else   { atomicAnd(wp, ~m); }
                }
            }
        }
    }
}

// ---------- Layer-2 partial sums from spike bitmask ----------
__global__ __launch_bounds__(256) void k_layer2_partial(const uint64_t* __restrict__ S1,
                                                        const float* __restrict__ W2T,
                                                        float* __restrict__ part,
                                                        int rowsTotal) {
    __shared__ float w[1024][10];   // 40 KB
    const int hs = blockIdx.y;
    for (int i = threadIdx.x; i < 1024 * 10; i += 256)
        w[i / 10][i % 10] = W2T[hs * 1024 * 10 + i];
    __syncthreads();

    const int row = blockIdx.x * 256 + threadIdx.x;
    const uint64_t* wp = S1 + (size_t)row * 64 + hs * 16;
    float acc[10] = {};
    for (int wi = 0; wi < 16; ++wi) {
        uint64_t m = wp[wi];
        while (m) {
            int bit = __builtin_ctzll(m);
            m &= m - 1;
            int hl = wi * 64 + bit;
#pragma unroll
            for (int o = 0; o < 10; ++o) acc[o] += w[hl][o];
        }
    }
    float* p = part + ((size_t)hs * rowsTotal + row) * 10;
#pragma unroll
    for (int o = 0; o < 10; ++o) p[o] = acc[o];
}

// ---------- Layer-2 IF recurrence + spike record ----------
__global__ __launch_bounds__(256) void k_layer2_rec(const float* __restrict__ part,
                                                    float* __restrict__ out) {
    const int i = blockIdx.x * 256 + threadIdx.x;
    if (i >= BATCH * OUTDIM) return;
    float v = 0.0f, rec = 0.0f;
    const int rowsTotal = T_TOTAL * BATCH;
    const int b = i / OUTDIM, o = i % OUTDIM;
    for (int t = 0; t < T_TOTAL; ++t) {
        const int r = t * BATCH + b;
        float sig = 0.0f;
#pragma unroll
        for (int hs = 0; hs < 4; ++hs)
            sig += part[((size_t)hs * rowsTotal + r) * 10 + o];
        v += sig;
        bool s = (v >= 1.0f);
        rec += s ? 1.0f : 0.0f;
        if (s) v = 0.0f;
    }
    out[i] = rec;
}

// ---------- launch ----------
extern "C" void kernel_launch(void* const* d_in, const int* in_sizes, int n_in,
                              void* d_out, int out_size, void* d_ws, size_t ws_size,
                              hipStream_t stream) {
    (void)in_sizes; (void)n_in; (void)out_size; (void)ws_size;
    const float* x  = (const float*)d_in[0];   // [32][1024][784]
    const float* W1 = (const float*)d_in[1];   // [4096][784]
    const float* W2 = (const float*)d_in[2];   // [10][4096]
    float* out = (float*)d_out;                // [1024][10]

    // ws layout (total ~230 MB)
    char* p = (char*)d_ws;
    float*    W2T   = (float*)p;    p += (size_t)HDIM * OUTDIM * 4;        // 160 KB
    float*    v1s   = (float*)p;    p += (size_t)BH * 4;                   // 16.8 MB
    ushort*   Bp    = (ushort*)p;   p += (size_t)HDIM * KP * 2;            // 19.4 MB
    ushort*   Ap    = (ushort*)p;   p += (size_t)MC * KP * 2;              // 38.8 MB
    float*    Z     = (float*)p;    p += (size_t)TC * BH * 4;              // 134.2 MB
    uint64_t* S1    = (uint64_t*)p; p += (size_t)T_TOTAL * WORDS_PER_T * 8;// 16.8 MB
    uint64_t* flags = (uint64_t*)p; p += (size_t)WORDS_PER_T * 8;          // 0.5 MB
    float*    part  = (float*)p;                                           // 5.2 MB

    k_transpose_w2<<<(HDIM * OUTDIM + 255) / 256, 256, 0, stream>>>(W2, W2T);
    k_split3<<<(HDIM * 400 + 255) / 256, 256, 0, stream>>>(W1, Bp, HDIM, 0);

    const int nch = T_TOTAL / TC;   // 4
    for (int c = 0; c < nch; ++c) {
        const float* xc = x + (size_t)c * MC * INDIM;
        k_split3<<<(MC * 400 + 255) / 256, 256, 0, stream>>>(xc, Ap, MC, 1);
        k_gemm_bf16<<<(MC / 256) * (HDIM / 256), 512, 0, stream>>>(Ap, Bp, Z);
        k_layer1_flag<<<BH / 256, 256, 0, stream>>>(Z, v1s, S1, flags, c * TC, c == 0);
    }
    k_fixup<<<BATCH, 256, 0, stream>>>(x, W1, flags, S1);
    k_layer2_partial<<<dim3(T_TOTAL * BATCH / 256, 4), 256, 0, stream>>>(
        S1, W2T, part, T_TOTAL * BATCH);
    k_layer2_rec<<<(BATCH * OUTDIM + 255) / 256, 256, 0, stream>>>(part, out);
}